// Round 20
// baseline (395.972 us; speedup 1.0000x reference)
//
#include <hip/hip_runtime.h>

#define DIM 120
#define WIN 4096          // o-window per LDS pass (16 KB)
#define BLOCK 256
#define NXCD 8

typedef float f32x4 __attribute__((ext_vector_type(4)));

// ---- preprocess: diff-based row_start + packed {a | c<<7 | o<<14, pal} ----
__global__ void pre_kernel(const int* __restrict__ oi, int K, int H,
                           int* __restrict__ row_start,
                           const int* __restrict__ i1, const int* __restrict__ i2,
                           const int* __restrict__ cb, const float* __restrict__ pal,
                           uint2* __restrict__ ent) {
    int k = blockIdx.x * blockDim.x + threadIdx.x;
    if (k < K) {
        uint2 e;
        e.x = (unsigned)i1[k] | ((unsigned)i2[k] << 7) | ((unsigned)oi[k] << 14);
        e.y = __float_as_uint(pal[cb[k]]);
        ent[k] = e;
        const int cur = oi[k];
        const int prev = (k == 0) ? -1 : oi[k - 1];
        for (int o = prev + 1; o <= cur; ++o) row_start[o] = k;
    } else if (k == K) {
        const int prev = oi[K - 1];
        for (int o = prev + 1; o <= H; ++o) row_start[o] = K;
    }
}

// ---- Main: block = one batch row b. Coalesced entry sweep -> LDS scatter-add
//      -> monotone contiguous NT dump. Write stream per block == fillBuffer. ----
__global__ __launch_bounds__(BLOCK, 8) void tp_kernel(
    const float* __restrict__ in1, const float* __restrict__ in2,
    const uint2* __restrict__ ent, const int* __restrict__ row_start,
    float* __restrict__ out, int H, int B) {
    __shared__ float s1[DIM];
    __shared__ float s2[DIM];
    __shared__ __align__(16) float owin[WIN];

    // bijective XCD-chunked swizzle on b (B % 8 == 0)
    int b = blockIdx.x;
    {
        const int q = B / NXCD;
        const int xcd = b % NXCD;
        b = xcd * q + b / NXCD;
    }

    const int tid = threadIdx.x;
    // stage the two 120-float rows
    for (int t = tid; t < 2 * DIM; t += BLOCK) {
        if (t < DIM) s1[t] = in1[(size_t)b * DIM + t];
        else         s2[t - DIM] = in2[(size_t)b * DIM + (t - DIM)];
    }
    for (int t = tid; t < WIN; t += BLOCK) owin[t] = 0.0f;
    __syncthreads();

    const int nwin = (H + WIN - 1) / WIN;
    for (int w = 0; w < nwin; ++w) {
        const int o0 = w * WIN;
        const int wlen = (H - o0 < WIN) ? (H - o0) : WIN;
        const int kw0 = row_start[o0];
        const int kw1 = row_start[o0 + wlen];

        // coalesced entry sweep; scatter-add into the LDS window
        for (int k = kw0 + tid; k < kw1; k += BLOCK) {
            const uint2 e = ent[k];
            const int a = e.x & 127;
            const int c = (e.x >> 7) & 127;
            const int o = (int)(e.x >> 14);
            const float v = __uint_as_float(e.y);
            atomicAdd(&owin[o - o0], v * s1[a] * s2[c]);
        }
        __syncthreads();

        // dump window as monotone contiguous NT 1KB bursts; re-zero for next
        for (int t = tid; t < (wlen >> 2); t += BLOCK) {
            const f32x4 val = *(const f32x4*)(owin + 4 * t);
            __builtin_nontemporal_store(
                val, (f32x4*)(out + (size_t)b * H + o0 + 4 * t));
            *(f32x4*)(owin + 4 * t) = (f32x4){0.f, 0.f, 0.f, 0.f};
        }
        __syncthreads();
    }
}

extern "C" void kernel_launch(void* const* d_in, const int* in_sizes, int n_in,
                              void* d_out, int out_size, void* d_ws, size_t ws_size,
                              hipStream_t stream) {
    const float* in1 = (const float*)d_in[0];
    const float* in2 = (const float*)d_in[1];
    const float* pal = (const float*)d_in[2];
    const int*   i1  = (const int*)d_in[3];
    const int*   i2  = (const int*)d_in[4];
    const int*   oi  = (const int*)d_in[5];
    const int*   cb  = (const int*)d_in[6];

    const int K = in_sizes[3];
    const int B = in_sizes[0] / DIM;   // 2048
    const int H = out_size / B;        // 14400

    uint2* ent = (uint2*)d_ws;
    int* row_start = (int*)((char*)d_ws + (size_t)K * sizeof(uint2));

    pre_kernel<<<(K + 1 + 255) / 256, 256, 0, stream>>>(oi, K, H, row_start,
                                                        i1, i2, cb, pal, ent);

    tp_kernel<<<dim3(B), BLOCK, 0, stream>>>(in1, in2, ent, row_start,
                                             (float*)d_out, H, B);
}

// Round 21
// 33.610 us; speedup vs baseline: 11.7814x; 11.7814x over previous
//
#include <hip/hip_runtime.h>

#define DIM 120
#define NB 16            // batch rows per block
#define NBP 20           // padded LDS stride in dwords (b128-aligned)
#define BLOCK 256        // one thread per output row
#define NG (NB / 4)      // float4 groups along b
#define NXCD 8
#define YCHUNK 16        // consecutive y-groups per XCD (128 = 8*16)
#define SMEM_FLOATS (2 * DIM * NBP)   // 19.2 KB staging, overlaid by 16 KB exchange

typedef float f32x4 __attribute__((ext_vector_type(4)));   // nt-store-legal vec4

// ---- Fused preprocess: diff-based CSR row pointers + packed entries ----
__global__ void pre_kernel(const int* __restrict__ oi, int K, int H,
                           int* __restrict__ row_start,
                           const int* __restrict__ i1, const int* __restrict__ i2,
                           const int* __restrict__ cb, const float* __restrict__ pal,
                           uint2* __restrict__ ent) {
    int k = blockIdx.x * blockDim.x + threadIdx.x;
    if (k < K) {
        uint2 e;
        e.x = (unsigned)i1[k] | ((unsigned)i2[k] << 16);
        e.y = __float_as_uint(pal[cb[k]]);
        ent[k] = e;
        const int cur = oi[k];
        const int prev = (k == 0) ? -1 : oi[k - 1];
        for (int o = prev + 1; o <= cur; ++o) row_start[o] = k;
    } else if (k == K) {
        const int prev = oi[K - 1];
        for (int o = prev + 1; o <= H; ++o) row_start[o] = K;
    }
}

// ---- Main: R16 hot loop + 2-D dispatch remap: XCD owns a contiguous y-chunk,
//      sweeps x fastest -> concurrent blocks per XCD write ADJACENT 1KB chunks
//      in a few dozen row-streams (fillBuffer-like), not ~576 scattered ones. ----
__global__ __launch_bounds__(BLOCK, 8) void tp_kernel(
    const float* __restrict__ in1, const float* __restrict__ in2,
    const uint2* __restrict__ ent, const int* __restrict__ row_start,
    float* __restrict__ out, int H, int nbx) {
    // linear dispatch id (x fastest), remapped:
    //   xcd = d % 8 owns y in [xcd*YCHUNK, (xcd+1)*YCHUNK); x fastest within.
    int x, y;
    {
        const int d = blockIdx.y * nbx + blockIdx.x;
        const int xcd = d % NXCD;
        const int pos = d / NXCD;          // 0 .. YCHUNK*nbx-1
        x = pos % nbx;
        y = xcd * YCHUNK + pos / nbx;
    }

    __shared__ __align__(16) float smem[SMEM_FLOATS];
    float* __restrict__ s1t = smem;
    float* __restrict__ s2t = smem + DIM * NBP;

    // --- stage NB batch-rows transposed to [d][b] ---
    const int b0 = y * NB;
    for (int t = threadIdx.x; t < 2 * DIM * NG; t += BLOCK) {
        const int arr = (t >= DIM * NG);
        const int c = arr ? t - DIM * NG : t;
        const int d = c % DIM;
        const int g = c / DIM;
        const float* __restrict__ src = arr ? in2 : in1;
        const size_t base = (size_t)(b0 + 4 * g) * DIM + d;
        float4 v;
        v.x = src[base + 0 * DIM];
        v.y = src[base + 1 * DIM];
        v.z = src[base + 2 * DIM];
        v.w = src[base + 3 * DIM];
        float* dst = arr ? s2t : s1t;
        *(float4*)(dst + d * NBP + 4 * g) = v;
    }
    __syncthreads();

    const int o0 = x * BLOCK;
    const int o = o0 + (int)threadIdx.x;
    const bool act = (o < H);

    float acc[NB];
#pragma unroll
    for (int b = 0; b < NB; ++b) acc[b] = 0.0f;

    if (act) {
        const int k0 = row_start[o];
        const int k1 = row_start[o + 1];
        for (int k = k0; k < k1; ++k) {
            const uint2 e = ent[k];
            const float4* __restrict__ pa = (const float4*)(s1t + (e.x & 0xffffu) * NBP);
            const float4* __restrict__ pc = (const float4*)(s2t + (e.x >> 16) * NBP);
            const float v = __uint_as_float(e.y);
#pragma unroll
            for (int j = 0; j < NG; ++j) {
                const float4 x4 = pa[j];
                const float4 y4 = pc[j];
                acc[4 * j + 0] = fmaf(v * x4.x, y4.x, acc[4 * j + 0]);
                acc[4 * j + 1] = fmaf(v * x4.y, y4.y, acc[4 * j + 1]);
                acc[4 * j + 2] = fmaf(v * x4.z, y4.z, acc[4 * j + 2]);
                acc[4 * j + 3] = fmaf(v * x4.w, y4.w, acc[4 * j + 3]);
            }
        }
    }
    __syncthreads();   // staging reads complete before overwriting smem

    if (o0 + BLOCK <= H) {
        // exchange: outbuf[b][t] overlaid on smem, stride-1 conflict-free
#pragma unroll
        for (int b = 0; b < NB; ++b)
            smem[b * BLOCK + threadIdx.x] = acc[b];
        __syncthreads();
        const int wave = threadIdx.x >> 6;
        const int lane = threadIdx.x & 63;
        f32x4 vv[NB / 4];
#pragma unroll
        for (int it = 0; it < NB / 4; ++it)
            vv[it] = *(const f32x4*)(smem + (it * 4 + wave) * BLOCK + 4 * lane);
#pragma unroll
        for (int it = 0; it < NB / 4; ++it)
            __builtin_nontemporal_store(
                vv[it],
                (f32x4*)(out + (size_t)(b0 + it * 4 + wave) * H + o0 + 4 * lane));
    } else if (act) {
#pragma unroll
        for (int b = 0; b < NB; ++b)
            __builtin_nontemporal_store(acc[b], &out[(size_t)(b0 + b) * H + o]);
    }
}

extern "C" void kernel_launch(void* const* d_in, const int* in_sizes, int n_in,
                              void* d_out, int out_size, void* d_ws, size_t ws_size,
                              hipStream_t stream) {
    const float* in1 = (const float*)d_in[0];
    const float* in2 = (const float*)d_in[1];
    const float* pal = (const float*)d_in[2];
    const int*   i1  = (const int*)d_in[3];
    const int*   i2  = (const int*)d_in[4];
    const int*   oi  = (const int*)d_in[5];
    const int*   cb  = (const int*)d_in[6];

    const int K = in_sizes[3];
    const int B = in_sizes[0] / DIM;   // 2048
    const int H = out_size / B;        // 14400

    uint2* ent = (uint2*)d_ws;
    int* row_start = (int*)((char*)d_ws + (size_t)K * sizeof(uint2));

    pre_kernel<<<(K + 1 + 255) / 256, 256, 0, stream>>>(oi, K, H, row_start,
                                                        i1, i2, cb, pal, ent);

    const int nbx = (H + BLOCK - 1) / BLOCK;   // 57
    dim3 grid(nbx, B / NB);                    // 57 x 128 (x fastest)
    tp_kernel<<<grid, BLOCK, 0, stream>>>(in1, in2, ent, row_start,
                                          (float*)d_out, H, nbx);
}

// Round 22
// 30.682 us; speedup vs baseline: 12.9058x; 1.0954x over previous
//
#include <hip/hip_runtime.h>

#define DIM 120
#define NB 16            // batch rows per block
#define NBP 20           // padded LDS stride in dwords (b128-aligned)
#define BLOCK 256        // one thread per output row
#define NG (NB / 4)      // float4 groups along b
#define NXCD 8
#define SMEM_FLOATS (2 * DIM * NBP)   // 4800 floats = 19.2 KB (>= 16 KB outbuf)

typedef float f32x4 __attribute__((ext_vector_type(4)));   // nt-store-legal vec4

// ---- Fused preprocess: diff-based CSR row pointers + packed entries ----
// Every output row has >=1 entry, so oi is dense: row boundaries found by
// comparing neighbors (no binary search).
__global__ void pre_kernel(const int* __restrict__ oi, int K, int H,
                           int* __restrict__ row_start,
                           const int* __restrict__ i1, const int* __restrict__ i2,
                           const int* __restrict__ cb, const float* __restrict__ pal,
                           uint2* __restrict__ ent) {
    int k = blockIdx.x * blockDim.x + threadIdx.x;
    if (k < K) {
        uint2 e;
        e.x = (unsigned)i1[k] | ((unsigned)i2[k] << 16);
        e.y = __float_as_uint(pal[cb[k]]);
        ent[k] = e;
        const int cur = oi[k];
        const int prev = (k == 0) ? -1 : oi[k - 1];
        for (int o = prev + 1; o <= cur; ++o) row_start[o] = k;
    } else if (k == K) {
        const int prev = oi[K - 1];
        for (int o = prev + 1; o <= H; ++o) row_start[o] = K;
    }
}

// ---- Main: R16 structure (best known): XCD-chunked x, LDS-staged batch tile,
//      per-row k-loop, LDS output exchange, hoisted reads, NT 1KB bursts. ----
__global__ __launch_bounds__(BLOCK, 8) void tp_kernel(
    const float* __restrict__ in1, const float* __restrict__ in2,
    const uint2* __restrict__ ent, const int* __restrict__ row_start,
    float* __restrict__ out, int H, int nbx) {
    // bijective XCD-chunked swizzle over the o-block dimension
    int x = blockIdx.x;
    {
        const int q = nbx / NXCD, r = nbx % NXCD;
        const int xcd = x % NXCD, pos = x / NXCD;
        x = (xcd < r) ? (xcd * (q + 1) + pos) : (r * (q + 1) + (xcd - r) * q + pos);
    }

    __shared__ __align__(16) float smem[SMEM_FLOATS];
    float* __restrict__ s1t = smem;
    float* __restrict__ s2t = smem + DIM * NBP;

    // --- stage NB batch-rows transposed to [d][b] ---
    const int b0 = blockIdx.y * NB;
    for (int t = threadIdx.x; t < 2 * DIM * NG; t += BLOCK) {
        const int arr = (t >= DIM * NG);
        const int c = arr ? t - DIM * NG : t;
        const int d = c % DIM;
        const int g = c / DIM;
        const float* __restrict__ src = arr ? in2 : in1;
        const size_t base = (size_t)(b0 + 4 * g) * DIM + d;
        float4 v;
        v.x = src[base + 0 * DIM];
        v.y = src[base + 1 * DIM];
        v.z = src[base + 2 * DIM];
        v.w = src[base + 3 * DIM];
        float* dst = arr ? s2t : s1t;
        *(float4*)(dst + d * NBP + 4 * g) = v;
    }
    __syncthreads();

    const int o0 = x * BLOCK;
    const int o = o0 + (int)threadIdx.x;
    const bool act = (o < H);

    float acc[NB];
#pragma unroll
    for (int b = 0; b < NB; ++b) acc[b] = 0.0f;

    if (act) {
        const int k0 = row_start[o];
        const int k1 = row_start[o + 1];
        for (int k = k0; k < k1; ++k) {
            const uint2 e = ent[k];
            const float4* __restrict__ pa = (const float4*)(s1t + (e.x & 0xffffu) * NBP);
            const float4* __restrict__ pc = (const float4*)(s2t + (e.x >> 16) * NBP);
            const float v = __uint_as_float(e.y);
#pragma unroll
            for (int j = 0; j < NG; ++j) {
                const float4 x4 = pa[j];
                const float4 y4 = pc[j];
                acc[4 * j + 0] = fmaf(v * x4.x, y4.x, acc[4 * j + 0]);
                acc[4 * j + 1] = fmaf(v * x4.y, y4.y, acc[4 * j + 1]);
                acc[4 * j + 2] = fmaf(v * x4.z, y4.z, acc[4 * j + 2]);
                acc[4 * j + 3] = fmaf(v * x4.w, y4.w, acc[4 * j + 3]);
            }
        }
    }
    __syncthreads();   // staging reads complete before overwriting smem

    if (o0 + BLOCK <= H) {
        // exchange: outbuf[b][t] overlaid on smem (16 KB), stride-1 conflict-free
#pragma unroll
        for (int b = 0; b < NB; ++b)
            smem[b * BLOCK + threadIdx.x] = acc[b];
        __syncthreads();
        // wave w owns b = 4*it + w; hoist all LDS reads, then back-to-back
        // 1KB contiguous NT dwordx4 bursts.
        const int wave = threadIdx.x >> 6;
        const int lane = threadIdx.x & 63;
        f32x4 vv[NB / 4];
#pragma unroll
        for (int it = 0; it < NB / 4; ++it)
            vv[it] = *(const f32x4*)(smem + (it * 4 + wave) * BLOCK + 4 * lane);
#pragma unroll
        for (int it = 0; it < NB / 4; ++it)
            __builtin_nontemporal_store(
                vv[it],
                (f32x4*)(out + (size_t)(b0 + it * 4 + wave) * H + o0 + 4 * lane));
    } else if (act) {
        // partial last tile: per-thread scalar nt stores
#pragma unroll
        for (int b = 0; b < NB; ++b)
            __builtin_nontemporal_store(acc[b], &out[(size_t)(b0 + b) * H + o]);
    }
}

extern "C" void kernel_launch(void* const* d_in, const int* in_sizes, int n_in,
                              void* d_out, int out_size, void* d_ws, size_t ws_size,
                              hipStream_t stream) {
    const float* in1 = (const float*)d_in[0];
    const float* in2 = (const float*)d_in[1];
    const float* pal = (const float*)d_in[2];
    const int*   i1  = (const int*)d_in[3];
    const int*   i2  = (const int*)d_in[4];
    const int*   oi  = (const int*)d_in[5];
    const int*   cb  = (const int*)d_in[6];

    const int K = in_sizes[3];
    const int B = in_sizes[0] / DIM;   // 2048
    const int H = out_size / B;        // 14400

    uint2* ent = (uint2*)d_ws;
    int* row_start = (int*)((char*)d_ws + (size_t)K * sizeof(uint2));

    pre_kernel<<<(K + 1 + 255) / 256, 256, 0, stream>>>(oi, K, H, row_start,
                                                        i1, i2, cb, pal, ent);

    const int nbx = (H + BLOCK - 1) / BLOCK;   // 57
    dim3 grid(nbx, B / NB);
    tp_kernel<<<grid, BLOCK, 0, stream>>>(in1, in2, ent, row_start,
                                          (float*)d_out, H, nbx);
}